// Round 11
// baseline (235.288 us; speedup 1.0000x reference)
//
#include <hip/hip_runtime.h>

typedef __bf16 bf16;
typedef __bf16 bf16x8 __attribute__((ext_vector_type(8)));
typedef float f32x4 __attribute__((ext_vector_type(4)));
typedef float f32x16 __attribute__((ext_vector_type(16)));

#define MFMA16(a, b, c) __builtin_amdgcn_mfma_f32_16x16x32_bf16((a), (b), (c), 0, 0, 0)
#define MFMA32(a, b, c) __builtin_amdgcn_mfma_f32_32x32x16_bf16((a), (b), (c), 0, 0, 0)

typedef const __attribute__((address_space(1))) uint32_t glb_u32;
typedef __attribute__((address_space(3))) uint32_t lds_u32;
#define GLOAD16(gp, lp) __builtin_amdgcn_global_load_lds((glb_u32*)(gp), (lds_u32*)(lp), 16, 0, 0)

// ---------------- elementwise f32 -> bf16 (8 per thread) ----------------
__global__ __launch_bounds__(256) void k_convX(const float* __restrict__ in, bf16* __restrict__ out) {
    size_t i = ((size_t)blockIdx.x * 256 + threadIdx.x) * 8;
    float4 a = *(const float4*)(in + i);
    float4 b = *(const float4*)(in + i + 4);
    bf16 e[8];
    e[0] = (bf16)a.x; e[1] = (bf16)a.y; e[2] = (bf16)a.z; e[3] = (bf16)a.w;
    e[4] = (bf16)b.x; e[5] = (bf16)b.y; e[6] = (bf16)b.z; e[7] = (bf16)b.w;
    uint4 u; __builtin_memcpy(&u, e, 16);
    *(uint4*)(out + i) = u;
}

// ------------- transpose+convert: in f32 [R][C] -> out bf16 [C][R] -------------
__global__ __launch_bounds__(256) void k_tconv(const float* __restrict__ in, bf16* __restrict__ out,
                                               int R, int C) {
    __shared__ float tile[64][65];
    int bx = blockIdx.x, by = blockIdx.y;
    int t = threadIdx.x;
    for (int i = 0; i < 16; ++i) {
        int e = i * 256 + t; int r = e >> 6, c = e & 63;
        tile[r][c] = in[(size_t)(by * 64 + r) * C + bx * 64 + c];
    }
    __syncthreads();
    for (int i = 0; i < 16; ++i) {
        int e = i * 256 + t; int r = e >> 6, c = e & 63;
        out[(size_t)(bx * 64 + r) * R + by * 64 + c] = (bf16)tile[c][r];
    }
}

// ------------- K [H][S][64] -> Kfrag (A-frag order for mfma32 QK^T) -------------
__global__ __launch_bounds__(256) void k_kpack(const uint4* __restrict__ in, uint4* __restrict__ out) {
    int c = blockIdx.x * 256 + threadIdx.x;     // 16 h * 128 tiles * 256 chunks
    int h = c >> 15;
    int r = c & 32767;
    int tile = r >> 8, kst = (r >> 6) & 3, l = r & 63;
    int t = tile * 32 + (l & 31);
    int dc = kst * 2 + (l >> 5);
    out[c] = in[((size_t)h * 4096 + t) * 8 + dc];
}

// ------------- V [H][S][64] -> Vfrag (B-frag order for PV) -------------
__global__ __launch_bounds__(256) void k_vtrans(const bf16* __restrict__ V, uint4* __restrict__ Vfr) {
    __shared__ bf16 tl[64][68];
    int t0 = blockIdx.x * 64;
    int h = blockIdx.y;
    int t = threadIdx.x;
    const bf16* Vh = V + (size_t)h * 4096 * 64;
    #pragma unroll
    for (int i = 0; i < 2; ++i) {
        int c = i * 256 + t; int row = c >> 3, ch = c & 7;
        uint4 v = *(const uint4*)(Vh + (size_t)(t0 + row) * 64 + ch * 8);
        bf16 e[8]; __builtin_memcpy(e, &v, 16);
        #pragma unroll
        for (int j = 0; j < 8; ++j) tl[row][ch * 8 + j] = e[j];
    }
    __syncthreads();
    uint4* Vfh = Vfr + (size_t)h * 32768;
    #pragma unroll
    for (int i = 0; i < 2; ++i) {
        int c = i * 256 + t; int d = c >> 3, tch = c & 7;
        bf16 e[8];
        #pragma unroll
        for (int j = 0; j < 8; ++j) e[j] = tl[tch * 8 + j][d];
        uint4 u; __builtin_memcpy(&u, e, 16);
        int tile = blockIdx.x * 2 + (tch >> 2);
        int chunk = tile * 256 + ((d >> 5) * 2 + ((tch >> 1) & 1)) * 64 + (d & 31) + 32 * (tch & 1);
        Vfh[chunk] = u;
    }
}

// ------------- 128x128 bf16 GEMM core -------------
__device__ __forceinline__ void gemm128_core(const bf16* __restrict__ A, const bf16* __restrict__ Bt,
                                             int r0, int c0, int Kd, char* As, char* Bs,
                                             f32x4 (&acc)[4][4]) {
    int t = threadIdx.x, l = t & 63, w = t >> 6;
    int g = l >> 4, li = l & 15;
    int wr = w >> 1, wc = w & 1;
    for (int k0 = 0; k0 < Kd; k0 += 64) {
        __syncthreads();
        #pragma unroll
        for (int i = 0; i < 4; ++i) {
            int slot = i * 256 + t;
            int row = slot >> 3;
            int ch  = (slot & 7) ^ (row & 7);
            int base = (i * 256 + w * 64) * 16;
            GLOAD16(A  + (size_t)(r0 + row) * Kd + k0 + ch * 8, As + base);
            GLOAD16(Bt + (size_t)(c0 + row) * Kd + k0 + ch * 8, Bs + base);
        }
        __syncthreads();
        __builtin_amdgcn_s_setprio(1);
        #pragma unroll
        for (int kk = 0; kk < 2; ++kk) {
            bf16x8 af[4], bfr[4];
            #pragma unroll
            for (int m = 0; m < 4; ++m) {
                int row = wr * 64 + m * 16 + li;
                af[m] = *(const bf16x8*)(As + ((row * 128 + kk * 64 + g * 16) ^ ((row & 7) << 4)));
            }
            #pragma unroll
            for (int n = 0; n < 4; ++n) {
                int row = wc * 64 + n * 16 + li;
                bfr[n] = *(const bf16x8*)(Bs + ((row * 128 + kk * 64 + g * 16) ^ ((row & 7) << 4)));
            }
            #pragma unroll
            for (int m = 0; m < 4; ++m)
                #pragma unroll
                for (int n = 0; n < 4; ++n)
                    acc[m][n] = MFMA16(af[m], bfr[n], acc[m][n]);
        }
        __builtin_amdgcn_s_setprio(0);
    }
}

// ------------- GEMM1: qkv = Xb @ WqkvT^T + bqkv; scatter to Q(scaled)/K/V [H][S][64] -------------
__global__ __launch_bounds__(256) void k_gemm_qkv(const bf16* __restrict__ Xb, const bf16* __restrict__ WqkvT,
                                                  const float* __restrict__ bqkv,
                                                  bf16* __restrict__ Q, bf16* __restrict__ K,
                                                  bf16* __restrict__ V) {
    __shared__ __align__(16) char As[16384];
    __shared__ __align__(16) char Bs[16384];
    int r0 = blockIdx.y * 128, c0 = blockIdx.x * 128;
    f32x4 acc[4][4] = {};
    gemm128_core(Xb, WqkvT, r0, c0, 1024, As, Bs, acc);
    int t = threadIdx.x, l = t & 63, w = t >> 6;
    int g = l >> 4, li = l & 15;
    int wr = w >> 1, wc = w & 1;
    int colbase = c0 + wc * 64;
    int sec = colbase >> 10;
    int head = (colbase & 1023) >> 6;
    bf16* dst = (sec == 0) ? Q : (sec == 1) ? K : V;
    // Q carries 1/sqrt(64) * log2(e) so attention softmax runs in exp2 domain
    float scale = (sec == 0) ? 0.125f * 1.44269504f : 1.0f;
    #pragma unroll
    for (int m = 0; m < 4; ++m)
        #pragma unroll
        for (int n = 0; n < 4; ++n) {
            int hd = n * 16 + li;
            float bias = bqkv[colbase + hd];
            #pragma unroll
            for (int r = 0; r < 4; ++r) {
                int row = r0 + wr * 64 + m * 16 + g * 4 + r;
                dst[(size_t)(head * 4096 + row) * 64 + hd] = (bf16)((acc[m][n][r] + bias) * scale);
            }
        }
}

// ------------- GEMM2: out = Ob @ WoT^T + bo (f32 out) -------------
__global__ __launch_bounds__(256) void k_gemm_out(const bf16* __restrict__ Ob, const bf16* __restrict__ WoT,
                                                  const float* __restrict__ bo, float* __restrict__ out) {
    __shared__ __align__(16) char As[16384];
    __shared__ __align__(16) char Bs[16384];
    int r0 = blockIdx.y * 128, c0 = blockIdx.x * 128;
    f32x4 acc[4][4] = {};
    gemm128_core(Ob, WoT, r0, c0, 1024, As, Bs, acc);
    int t = threadIdx.x, l = t & 63, w = t >> 6;
    int g = l >> 4, li = l & 15;
    int wr = w >> 1, wc = w & 1;
    #pragma unroll
    for (int m = 0; m < 4; ++m)
        #pragma unroll
        for (int n = 0; n < 4; ++n) {
            int col = c0 + wc * 64 + n * 16 + li;
            float bias = bo[col];
            #pragma unroll
            for (int r = 0; r < 4; ++r) {
                int row = r0 + wr * 64 + m * 16 + g * 4 + r;
                out[(size_t)row * 1024 + col] = acc[m][n][r] + bias;
            }
        }
}

// pack two f32 -> u32 of two bf16
__device__ __forceinline__ unsigned pkbf(float a, float b) {
    bf16 h0 = (bf16)a, h1 = (bf16)b;
    unsigned short u0, u1;
    __builtin_memcpy(&u0, &h0, 2); __builtin_memcpy(&u1, &h1, 2);
    return (unsigned)u0 | ((unsigned)u1 << 16);
}

// ------------- causal flash attention, swapped-QK 32x32, SHARED LDS K/V stream ---------------
// 512 blocks x 256 threads (4 waves). Block = 4 consecutive q-tiles {4G..4G+3}; wave w owns
// q-tile jj=4G+w. ONE shared frag-packed K/V stream, double-buffered in LDS via
// global_load_lds (frag layout is lane-linear -> linear dest + conflict-free ds_read_b128).
// Cuts cache read traffic 4x vs per-wave private streams (the R7-R10 ~10 TB/s wall).
// G = u<16 ? u : 47-u  ->  co-resident block pairs (c, c+256) sum to 136 tiles per CU.
// h = bid&15 keeps XCD head affinity. No split-KV -> no merge; each wave writes its rows.
__global__ __launch_bounds__(256) void k_attn(const bf16* __restrict__ Q, const uint4* __restrict__ Kfr,
                                              const uint4* __restrict__ Vfr, bf16* __restrict__ O) {
    __shared__ __align__(16) char Kb[2][4096];   // one 32-t K tile, frag order, dbuf
    __shared__ __align__(16) char Vb[2][4096];   // one 32-t V tile, frag order, dbuf
    int bid = blockIdx.x;
    int h = bid & 15;                 // h%8 == bid%8 -> XCD head affinity
    int u = bid >> 4;                 // 0..31
    int G = (u < 16) ? u : 47 - u;    // complementary co-residency: pairs sum to 31
    int tid = threadIdx.x;
    int w = tid >> 6;
    int l = tid & 63;
    int lc = l & 31, hi = l >> 5;
    int hi4 = hi * 4, hi8 = hi * 8;
    int jj = 4 * G + w;               // this wave's q-tile
    int nt = 4 * G + 4;               // block-uniform KV stream length
    const bf16* Qh = Q + (size_t)h * 4096 * 64;
    const uint4* Kh = Kfr + (size_t)h * 32768;
    const uint4* Vh = Vfr + (size_t)h * 32768;
    int ldsbase = w * 1024;           // wave-uniform gload_lds dest base

    bf16x8 qf[4];
    #pragma unroll
    for (int kst = 0; kst < 4; ++kst)
        qf[kst] = *(const bf16x8*)(Qh + (size_t)(jj * 32 + lc) * 64 + kst * 16 + hi8);
    f32x16 oacc[2] = {};
    float m = -1e30f, lsum = 0.f;

    // prologue: stage tile 0 -> buf 0
    GLOAD16(Kh + tid, Kb[0] + ldsbase);
    GLOAD16(Vh + tid, Vb[0] + ldsbase);
    int cur = 0;
    for (int tt = 0; tt < nt; ++tt) {
        __syncthreads();   // drains vmcnt: buf[cur] ready; prior reads of buf[cur^1] done
        if (tt + 1 < nt) {
            GLOAD16(Kh + (size_t)(tt + 1) * 256 + tid, Kb[cur ^ 1] + ldsbase);
            GLOAD16(Vh + (size_t)(tt + 1) * 256 + tid, Vb[cur ^ 1] + ldsbase);
        }
        if (tt <= jj) {
            // S^T = K Q^T : col=lc -> q, row(reg,hi) -> t
            f32x16 sacc = {};
            #pragma unroll
            for (int kst = 0; kst < 4; ++kst) {
                bf16x8 kk = *(const bf16x8*)(Kb[cur] + (kst * 64 + l) * 16);
                sacc = MFMA32(kk, qf[kst], sacc);
            }
            if (tt == jj) {   // diagonal tile: mask t_local > q_local
                #pragma unroll
                for (int r = 0; r < 16; ++r) {
                    int tloc = (r & 3) + 8 * (r >> 2) + hi4;
                    if (tloc > lc) sacc[r] = -1e30f;
                }
            }
            // row max
            float t8[8];
            #pragma unroll
            for (int r = 0; r < 8; ++r) t8[r] = fmaxf(sacc[r], sacc[r + 8]);
            float t4a = fmaxf(fmaxf(t8[0], t8[1]), fmaxf(t8[2], t8[3]));
            float t4b = fmaxf(fmaxf(t8[4], t8[5]), fmaxf(t8[6], t8[7]));
            float pm = fmaxf(t4a, t4b);
            pm = fmaxf(pm, __shfl_xor(pm, 32));
            // defer-max rescale (THR=8 log2-units)
            if (!__all(pm - m <= 8.0f)) {
                float mn = fmaxf(m, pm);
                float al = exp2f(m - mn);
                #pragma unroll
                for (int r = 0; r < 16; ++r) {
                    int ql = (r & 3) + 8 * (r >> 2) + hi4;
                    float alb = __shfl(al, ql);
                    oacc[0][r] *= alb;
                    oacc[1][r] *= alb;
                }
                lsum *= al;
                m = mn;
            }
            float pv[16];
            float rs = 0.f;
            #pragma unroll
            for (int r = 0; r < 16; ++r) { pv[r] = exp2f(sacc[r] - m); rs += pv[r]; }
            lsum += rs;
            // PA frags via pack + lane^32 swap; PV
            #pragma unroll
            for (int ks = 0; ks < 2; ++ks) {
                int b = ks * 8;
                unsigned a0 = pkbf(pv[b + 0], pv[b + 1]), b0 = pkbf(pv[b + 4], pv[b + 5]);
                unsigned a1 = pkbf(pv[b + 2], pv[b + 3]), b1v = pkbf(pv[b + 6], pv[b + 7]);
                unsigned xa0 = (unsigned)__shfl_xor((int)a0, 32);
                unsigned xb0 = (unsigned)__shfl_xor((int)b0, 32);
                unsigned xa1 = (unsigned)__shfl_xor((int)a1, 32);
                unsigned xb1 = (unsigned)__shfl_xor((int)b1v, 32);
                unsigned wsq[4];
                wsq[0] = hi ? xb0 : a0;
                wsq[1] = hi ? xb1 : a1;
                wsq[2] = hi ? b0 : xa0;
                wsq[3] = hi ? b1v : xa1;
                bf16x8 pa; __builtin_memcpy(&pa, wsq, 16);
                #pragma unroll
                for (int jt = 0; jt < 2; ++jt) {
                    bf16x8 vv = *(const bf16x8*)(Vb[cur] + ((jt * 2 + ks) * 64 + l) * 16);
                    oacc[jt] = MFMA32(pa, vv, oacc[jt]);
                }
            }
        }
        cur ^= 1;
    }
    // epilogue: combine halves, normalize, write O [S][H*64]
    lsum += __shfl_xor(lsum, 32);
    float inv = 1.0f / lsum;
    int q0 = jj * 32;
    #pragma unroll
    for (int r = 0; r < 16; ++r) {
        int ql = (r & 3) + 8 * (r >> 2) + hi4;
        float ib = __shfl(inv, ql);
        int row = q0 + ql;
        O[(size_t)row * 1024 + h * 64 + lc]      = (bf16)(oacc[0][r] * ib);
        O[(size_t)row * 1024 + h * 64 + 32 + lc] = (bf16)(oacc[1][r] * ib);
    }
}

extern "C" void kernel_launch(void* const* d_in, const int* in_sizes, int n_in,
                              void* d_out, int out_size, void* d_ws, size_t ws_size,
                              hipStream_t stream) {
    const float* X    = (const float*)d_in[0];   // [1,4096,1024]
    const float* Wqkv = (const float*)d_in[1];   // [1024,3072]
    const float* bqkv = (const float*)d_in[2];   // [3072]
    const float* Wo   = (const float*)d_in[3];   // [1024,1024]
    const float* bo   = (const float*)d_in[4];   // [1024]
    float* out = (float*)d_out;

    char* ws = (char*)d_ws;
    const size_t MB = 1024 * 1024;
    bf16*  Xb    = (bf16*)(ws);             //  8 MB [4096][1024]; dead after gemm_qkv
    bf16*  WqkvT = (bf16*)(ws + 8  * MB);   //  6 MB [3072][1024]
    bf16*  WoT   = (bf16*)(ws + 14 * MB);   //  2 MB [1024][1024]
    bf16*  Qb    = (bf16*)(ws + 16 * MB);   //  8 MB [16][4096][64]
    bf16*  Kb    = (bf16*)(ws + 24 * MB);   //  8 MB [16][4096][64]
    bf16*  Vb    = (bf16*)(ws + 32 * MB);   //  8 MB [16][4096][64]
    uint4* Kfr   = (uint4*)(ws + 40 * MB);  //  8 MB frag-packed K
    uint4* Vfr   = (uint4*)(ws + 48 * MB);  //  8 MB frag-packed V^T
    bf16*  Ob    = Xb;                      //  alias: Xb dead before attn writes Ob

    k_convX<<<2048, 256, 0, stream>>>(X, Xb);
    k_tconv<<<dim3(48, 16), 256, 0, stream>>>(Wqkv, WqkvT, 1024, 3072);
    k_tconv<<<dim3(16, 16), 256, 0, stream>>>(Wo, WoT, 1024, 1024);
    k_gemm_qkv<<<dim3(24, 32), 256, 0, stream>>>(Xb, WqkvT, bqkv, Qb, Kb, Vb);
    k_kpack<<<2048, 256, 0, stream>>>((const uint4*)Kb, Kfr);
    k_vtrans<<<dim3(64, 16), 256, 0, stream>>>(Vb, Vfr);
    k_attn<<<512, 256, 0, stream>>>(Qb, Kfr, Vfr, Ob);
    k_gemm_out<<<dim3(8, 32), 256, 0, stream>>>(Ob, WoT, bo, out);
}

// Round 12
// 161.477 us; speedup vs baseline: 1.4571x; 1.4571x over previous
//
#include <hip/hip_runtime.h>

typedef __bf16 bf16;
typedef __bf16 bf16x8 __attribute__((ext_vector_type(8)));
typedef float f32x4 __attribute__((ext_vector_type(4)));
typedef float f32x16 __attribute__((ext_vector_type(16)));
typedef unsigned u32x2 __attribute__((ext_vector_type(2)));

#define MFMA16(a, b, c) __builtin_amdgcn_mfma_f32_16x16x32_bf16((a), (b), (c), 0, 0, 0)
#define MFMA32(a, b, c) __builtin_amdgcn_mfma_f32_32x32x16_bf16((a), (b), (c), 0, 0, 0)

typedef const __attribute__((address_space(1))) uint32_t glb_u32;
typedef __attribute__((address_space(3))) uint32_t lds_u32;
#define GLOAD16(gp, lp) __builtin_amdgcn_global_load_lds((glb_u32*)(gp), (lds_u32*)(lp), 16, 0, 0)

// ---------------- elementwise f32 -> bf16 (8 per thread) ----------------
__global__ __launch_bounds__(256) void k_convX(const float* __restrict__ in, bf16* __restrict__ out) {
    size_t i = ((size_t)blockIdx.x * 256 + threadIdx.x) * 8;
    float4 a = *(const float4*)(in + i);
    float4 b = *(const float4*)(in + i + 4);
    bf16 e[8];
    e[0] = (bf16)a.x; e[1] = (bf16)a.y; e[2] = (bf16)a.z; e[3] = (bf16)a.w;
    e[4] = (bf16)b.x; e[5] = (bf16)b.y; e[6] = (bf16)b.z; e[7] = (bf16)b.w;
    uint4 u; __builtin_memcpy(&u, e, 16);
    *(uint4*)(out + i) = u;
}

// ------------- transpose+convert: in f32 [R][C] -> out bf16 [C][R] -------------
__global__ __launch_bounds__(256) void k_tconv(const float* __restrict__ in, bf16* __restrict__ out,
                                               int R, int C) {
    __shared__ float tile[64][65];
    int bx = blockIdx.x, by = blockIdx.y;
    int t = threadIdx.x;
    for (int i = 0; i < 16; ++i) {
        int e = i * 256 + t; int r = e >> 6, c = e & 63;
        tile[r][c] = in[(size_t)(by * 64 + r) * C + bx * 64 + c];
    }
    __syncthreads();
    for (int i = 0; i < 16; ++i) {
        int e = i * 256 + t; int r = e >> 6, c = e & 63;
        out[(size_t)(bx * 64 + r) * R + by * 64 + c] = (bf16)tile[c][r];
    }
}

// ------------- K [H][S][64] -> Kfrag (A-frag order for mfma32 QK^T) -------------
__global__ __launch_bounds__(256) void k_kpack(const uint4* __restrict__ in, uint4* __restrict__ out) {
    int c = blockIdx.x * 256 + threadIdx.x;     // 16 h * 128 tiles * 256 chunks
    int h = c >> 15;
    int r = c & 32767;
    int tile = r >> 8, kst = (r >> 6) & 3, l = r & 63;
    int t = tile * 32 + (l & 31);
    int dc = kst * 2 + (l >> 5);
    out[c] = in[((size_t)h * 4096 + t) * 8 + dc];
}

// ------------- V [H][S][64] -> Vfrag (B-frag order for PV) -------------
__global__ __launch_bounds__(256) void k_vtrans(const bf16* __restrict__ V, uint4* __restrict__ Vfr) {
    __shared__ bf16 tl[64][68];
    int t0 = blockIdx.x * 64;
    int h = blockIdx.y;
    int t = threadIdx.x;
    const bf16* Vh = V + (size_t)h * 4096 * 64;
    #pragma unroll
    for (int i = 0; i < 2; ++i) {
        int c = i * 256 + t; int row = c >> 3, ch = c & 7;
        uint4 v = *(const uint4*)(Vh + (size_t)(t0 + row) * 64 + ch * 8);
        bf16 e[8]; __builtin_memcpy(e, &v, 16);
        #pragma unroll
        for (int j = 0; j < 8; ++j) tl[row][ch * 8 + j] = e[j];
    }
    __syncthreads();
    uint4* Vfh = Vfr + (size_t)h * 32768;
    #pragma unroll
    for (int i = 0; i < 2; ++i) {
        int c = i * 256 + t; int d = c >> 3, tch = c & 7;
        bf16 e[8];
        #pragma unroll
        for (int j = 0; j < 8; ++j) e[j] = tl[tch * 8 + j][d];
        uint4 u; __builtin_memcpy(&u, e, 16);
        int tile = blockIdx.x * 2 + (tch >> 2);
        int chunk = tile * 256 + ((d >> 5) * 2 + ((tch >> 1) & 1)) * 64 + (d & 31) + 32 * (tch & 1);
        Vfh[chunk] = u;
    }
}

// ------------- 128x128 bf16 GEMM core -------------
__device__ __forceinline__ void gemm128_core(const bf16* __restrict__ A, const bf16* __restrict__ Bt,
                                             int r0, int c0, int Kd, char* As, char* Bs,
                                             f32x4 (&acc)[4][4]) {
    int t = threadIdx.x, l = t & 63, w = t >> 6;
    int g = l >> 4, li = l & 15;
    int wr = w >> 1, wc = w & 1;
    for (int k0 = 0; k0 < Kd; k0 += 64) {
        __syncthreads();
        #pragma unroll
        for (int i = 0; i < 4; ++i) {
            int slot = i * 256 + t;
            int row = slot >> 3;
            int ch  = (slot & 7) ^ (row & 7);
            int base = (i * 256 + w * 64) * 16;
            GLOAD16(A  + (size_t)(r0 + row) * Kd + k0 + ch * 8, As + base);
            GLOAD16(Bt + (size_t)(c0 + row) * Kd + k0 + ch * 8, Bs + base);
        }
        __syncthreads();
        __builtin_amdgcn_s_setprio(1);
        #pragma unroll
        for (int kk = 0; kk < 2; ++kk) {
            bf16x8 af[4], bfr[4];
            #pragma unroll
            for (int m = 0; m < 4; ++m) {
                int row = wr * 64 + m * 16 + li;
                af[m] = *(const bf16x8*)(As + ((row * 128 + kk * 64 + g * 16) ^ ((row & 7) << 4)));
            }
            #pragma unroll
            for (int n = 0; n < 4; ++n) {
                int row = wc * 64 + n * 16 + li;
                bfr[n] = *(const bf16x8*)(Bs + ((row * 128 + kk * 64 + g * 16) ^ ((row & 7) << 4)));
            }
            #pragma unroll
            for (int m = 0; m < 4; ++m)
                #pragma unroll
                for (int n = 0; n < 4; ++n)
                    acc[m][n] = MFMA16(af[m], bfr[n], acc[m][n]);
        }
        __builtin_amdgcn_s_setprio(0);
    }
}

// ------------- GEMM1: qkv = Xb @ WqkvT^T + bqkv; scatter to Q(scaled)/K/V [H][S][64] -------------
__global__ __launch_bounds__(256) void k_gemm_qkv(const bf16* __restrict__ Xb, const bf16* __restrict__ WqkvT,
                                                  const float* __restrict__ bqkv,
                                                  bf16* __restrict__ Q, bf16* __restrict__ K,
                                                  bf16* __restrict__ V) {
    __shared__ __align__(16) char As[16384];
    __shared__ __align__(16) char Bs[16384];
    int r0 = blockIdx.y * 128, c0 = blockIdx.x * 128;
    f32x4 acc[4][4] = {};
    gemm128_core(Xb, WqkvT, r0, c0, 1024, As, Bs, acc);
    int t = threadIdx.x, l = t & 63, w = t >> 6;
    int g = l >> 4, li = l & 15;
    int wr = w >> 1, wc = w & 1;
    int colbase = c0 + wc * 64;
    int sec = colbase >> 10;
    int head = (colbase & 1023) >> 6;
    bf16* dst = (sec == 0) ? Q : (sec == 1) ? K : V;
    // Q carries 1/sqrt(64) * log2(e) so attention softmax runs in exp2 domain
    float scale = (sec == 0) ? 0.125f * 1.44269504f : 1.0f;
    #pragma unroll
    for (int m = 0; m < 4; ++m)
        #pragma unroll
        for (int n = 0; n < 4; ++n) {
            int hd = n * 16 + li;
            float bias = bqkv[colbase + hd];
            #pragma unroll
            for (int r = 0; r < 4; ++r) {
                int row = r0 + wr * 64 + m * 16 + g * 4 + r;
                dst[(size_t)(head * 4096 + row) * 64 + hd] = (bf16)((acc[m][n][r] + bias) * scale);
            }
        }
}

// ------------- GEMM2: out = Ob @ WoT^T + bo (f32 out) -------------
__global__ __launch_bounds__(256) void k_gemm_out(const bf16* __restrict__ Ob, const bf16* __restrict__ WoT,
                                                  const float* __restrict__ bo, float* __restrict__ out) {
    __shared__ __align__(16) char As[16384];
    __shared__ __align__(16) char Bs[16384];
    int r0 = blockIdx.y * 128, c0 = blockIdx.x * 128;
    f32x4 acc[4][4] = {};
    gemm128_core(Ob, WoT, r0, c0, 1024, As, Bs, acc);
    int t = threadIdx.x, l = t & 63, w = t >> 6;
    int g = l >> 4, li = l & 15;
    int wr = w >> 1, wc = w & 1;
    #pragma unroll
    for (int m = 0; m < 4; ++m)
        #pragma unroll
        for (int n = 0; n < 4; ++n) {
            int col = c0 + wc * 64 + n * 16 + li;
            float bias = bo[col];
            #pragma unroll
            for (int r = 0; r < 4; ++r) {
                int row = r0 + wr * 64 + m * 16 + g * 4 + r;
                out[(size_t)row * 1024 + col] = acc[m][n][r] + bias;
            }
        }
}

// pack two f32 -> u32 of two bf16
__device__ __forceinline__ unsigned pkbf(float a, float b) {
    bf16 h0 = (bf16)a, h1 = (bf16)b;
    unsigned short u0, u1;
    __builtin_memcpy(&u0, &h0, 2); __builtin_memcpy(&u1, &h1, 2);
    return (unsigned)u0 | ((unsigned)u1 << 16);
}

// ------------- causal flash attention, swapped-QK 32x32, register-direct K/V ------------------
// R9 structure (best measured: 100us) + instruction-reduction micro-opts:
//  * permlane32_swap builds PA frags (4 VALU ops replace 8 ds-shuffles + 8 cndmask / tile)
//  * max3-friendly row-max tree
//  * s_setprio(1) around MFMA clusters (T5)
// 2048 blocks x 128 threads (2 waves). Block = ONE 32-row q-tile jj; waves split KV in half;
// wave1 posts partial (O,m,l) to LDS; wave0 merges and writes.
// u=bid>>4, jj = u<64 ? u : 191-u -> per-CU balanced. h=bid&15 keeps XCD head affinity.
__global__ __launch_bounds__(128) void k_attn(const bf16* __restrict__ Q, const uint4* __restrict__ Kfr,
                                              const uint4* __restrict__ Vfr, bf16* __restrict__ O) {
    __shared__ float Op[32][64];      // wave1 partial O [q][d]
    __shared__ float Ml[2][32];       // wave1 partial {m,l}[q]
    int bid = blockIdx.x;
    int h = bid & 15;                 // h%8 == bid%8 -> XCD head affinity
    int u = bid >> 4;                 // 0..127
    int jj = (u < 64) ? u : 191 - u;  // per-CU balanced q-tile index
    int w = threadIdx.x >> 6;
    int l = threadIdx.x & 63;
    int lc = l & 31, hi = l >> 5;
    int hi4 = hi * 4, hi8 = hi * 8;
    const bf16* Qh = Q + (size_t)h * 4096 * 64;
    const uint4* Kh = Kfr + (size_t)h * 32768;
    const uint4* Vh = Vfr + (size_t)h * 32768;
    int nt = jj + 1;
    int hA = (nt + 1) >> 1;
    int tb = w ? hA : 0;
    int te = w ? nt : hA;

    f32x16 oacc[2] = {};
    float m = -1e30f, lsum = 0.f;
    uint4 kA[4], vA[4], kB[4], vB[4];
    bf16x8 qf[4];
    #pragma unroll
    for (int kst = 0; kst < 4; ++kst)
        qf[kst] = *(const bf16x8*)(Qh + (size_t)(jj * 32 + lc) * 64 + kst * 16 + hi8);

    auto compute = [&](int tt, uint4 (&kf)[4], uint4 (&vf)[4]) {
        // S^T = K Q^T : col=lc -> q, row(reg,hi) -> t
        f32x16 sacc = {};
        __builtin_amdgcn_s_setprio(1);
        #pragma unroll
        for (int kst = 0; kst < 4; ++kst) {
            bf16x8 kk; __builtin_memcpy(&kk, &kf[kst], 16);
            sacc = MFMA32(kk, qf[kst], sacc);
        }
        __builtin_amdgcn_s_setprio(0);
        if (tt == jj) {   // diagonal tile: mask t_local > q_local
            #pragma unroll
            for (int r = 0; r < 16; ++r) {
                int tloc = (r & 3) + 8 * (r >> 2) + hi4;
                if (tloc > lc) sacc[r] = -1e30f;
            }
        }
        // row max (max3-friendly tree)
        float t8[8];
        #pragma unroll
        for (int r = 0; r < 8; ++r) t8[r] = fmaxf(sacc[r], sacc[r + 8]);
        float ta = fmaxf(fmaxf(t8[0], t8[1]), t8[2]);
        float tb3 = fmaxf(fmaxf(t8[3], t8[4]), t8[5]);
        float tc = fmaxf(t8[6], t8[7]);
        float pm = fmaxf(fmaxf(ta, tb3), tc);
        pm = fmaxf(pm, __shfl_xor(pm, 32));
        // defer-max rescale (THR=8 log2-units)
        if (!__all(pm - m <= 8.0f)) {
            float mn = fmaxf(m, pm);
            float al = exp2f(m - mn);
            #pragma unroll
            for (int r = 0; r < 16; ++r) {
                int ql = (r & 3) + 8 * (r >> 2) + hi4;
                float alb = __shfl(al, ql);
                oacc[0][r] *= alb;
                oacc[1][r] *= alb;
            }
            lsum *= al;
            m = mn;
        }
        float pv[16];
        float rs0 = 0.f, rs1 = 0.f;
        #pragma unroll
        for (int r = 0; r < 8; ++r) {
            pv[r]     = exp2f(sacc[r] - m);     rs0 += pv[r];
            pv[r + 8] = exp2f(sacc[r + 8] - m); rs1 += pv[r + 8];
        }
        lsum += rs0 + rs1;
        // PA frags: pack pairs to bf16 words, permlane32_swap redistributes halves.
        // swap(a,b) -> r[0]={a_lo,b_lo} (lo lanes keep a, hi lanes get b_lo),
        //              r[1]={a_hi,b_hi}  — exactly wsq[0]/wsq[2] of the shfl_xor version.
        #pragma unroll
        for (int ks = 0; ks < 2; ++ks) {
            int b = ks * 8;
            unsigned a0 = pkbf(pv[b + 0], pv[b + 1]), a1 = pkbf(pv[b + 2], pv[b + 3]);
            unsigned b0 = pkbf(pv[b + 4], pv[b + 5]), b1 = pkbf(pv[b + 6], pv[b + 7]);
            u32x2 r0 = __builtin_amdgcn_permlane32_swap(a0, b0, false, false);
            u32x2 r1 = __builtin_amdgcn_permlane32_swap(a1, b1, false, false);
            unsigned wsq[4] = { r0[0], r1[0], r0[1], r1[1] };
            bf16x8 pa; __builtin_memcpy(&pa, wsq, 16);
            __builtin_amdgcn_s_setprio(1);
            #pragma unroll
            for (int jt = 0; jt < 2; ++jt) {
                bf16x8 vv; __builtin_memcpy(&vv, &vf[jt * 2 + ks], 16);
                oacc[jt] = MFMA32(pa, vv, oacc[jt]);
            }
            __builtin_amdgcn_s_setprio(0);
        }
    };

    // KV loop over [tb, te), register double-buffered one tile ahead
    if (te > tb) {
        #pragma unroll
        for (int i = 0; i < 4; ++i) {
            kA[i] = Kh[(size_t)tb * 256 + i * 64 + l];
            vA[i] = Vh[(size_t)tb * 256 + i * 64 + l];
        }
        int i = tb;
        for (; i + 2 <= te; i += 2) {
            const uint4* Kn = Kh + (size_t)(i + 1) * 256;
            const uint4* Vn = Vh + (size_t)(i + 1) * 256;
            #pragma unroll
            for (int q = 0; q < 4; ++q) { kB[q] = Kn[q * 64 + l]; vB[q] = Vn[q * 64 + l]; }
            compute(i, kA, vA);
            if (i + 2 < te) {
                const uint4* K2 = Kh + (size_t)(i + 2) * 256;
                const uint4* V2 = Vh + (size_t)(i + 2) * 256;
                #pragma unroll
                for (int q = 0; q < 4; ++q) { kA[q] = K2[q * 64 + l]; vA[q] = V2[q * 64 + l]; }
            }
            compute(i + 1, kB, vB);
        }
        if ((te - tb) & 1) compute(te - 1, kA, vA);
    }
    lsum += __shfl_xor(lsum, 32);

    if (w == 1) {
        #pragma unroll
        for (int r = 0; r < 16; ++r) {
            int ql = (r & 3) + 8 * (r >> 2) + hi4;
            Op[ql][lc]      = oacc[0][r];
            Op[ql][32 + lc] = oacc[1][r];
        }
        if (hi == 0) { Ml[0][lc] = m; Ml[1][lc] = lsum; }
    }
    __syncthreads();
    if (w == 0) {
        float mo = Ml[0][lc], lo = Ml[1][lc];
        float mm = fmaxf(m, mo);
        float alr = exp2f(m - mm), alo = exp2f(mo - mm);
        float lf = lsum * alr + lo * alo;
        float inv = 1.0f / lf;
        float fr = alr * inv, fo = alo * inv;
        int q0 = jj * 32;
        #pragma unroll
        for (int r = 0; r < 16; ++r) {
            int ql = (r & 3) + 8 * (r >> 2) + hi4;
            float frb = __shfl(fr, ql), fob = __shfl(fo, ql);
            float o0 = oacc[0][r] * frb + Op[ql][lc]      * fob;
            float o1 = oacc[1][r] * frb + Op[ql][32 + lc] * fob;
            int row = q0 + ql;
            O[(size_t)row * 1024 + h * 64 + lc]      = (bf16)o0;
            O[(size_t)row * 1024 + h * 64 + 32 + lc] = (bf16)o1;
        }
    }
}

extern "C" void kernel_launch(void* const* d_in, const int* in_sizes, int n_in,
                              void* d_out, int out_size, void* d_ws, size_t ws_size,
                              hipStream_t stream) {
    const float* X    = (const float*)d_in[0];   // [1,4096,1024]
    const float* Wqkv = (const float*)d_in[1];   // [1024,3072]
    const float* bqkv = (const float*)d_in[2];   // [3072]
    const float* Wo   = (const float*)d_in[3];   // [1024,1024]
    const float* bo   = (const float*)d_in[4];   // [1024]
    float* out = (float*)d_out;

    char* ws = (char*)d_ws;
    const size_t MB = 1024 * 1024;
    bf16*  Xb    = (bf16*)(ws);             //  8 MB [4096][1024]; dead after gemm_qkv
    bf16*  WqkvT = (bf16*)(ws + 8  * MB);   //  6 MB [3072][1024]
    bf16*  WoT   = (bf16*)(ws + 14 * MB);   //  2 MB [1024][1024]
    bf16*  Qb    = (bf16*)(ws + 16 * MB);   //  8 MB [16][4096][64]
    bf16*  Kb    = (bf16*)(ws + 24 * MB);   //  8 MB [16][4096][64]
    bf16*  Vb    = (bf16*)(ws + 32 * MB);   //  8 MB [16][4096][64]
    uint4* Kfr   = (uint4*)(ws + 40 * MB);  //  8 MB frag-packed K
    uint4* Vfr   = (uint4*)(ws + 48 * MB);  //  8 MB frag-packed V^T
    bf16*  Ob    = Xb;                      //  alias: Xb dead before attn writes Ob

    k_convX<<<2048, 256, 0, stream>>>(X, Xb);
    k_tconv<<<dim3(48, 16), 256, 0, stream>>>(Wqkv, WqkvT, 1024, 3072);
    k_tconv<<<dim3(16, 16), 256, 0, stream>>>(Wo, WoT, 1024, 1024);
    k_gemm_qkv<<<dim3(24, 32), 256, 0, stream>>>(Xb, WqkvT, bqkv, Qb, Kb, Vb);
    k_kpack<<<2048, 256, 0, stream>>>((const uint4*)Kb, Kfr);
    k_vtrans<<<dim3(64, 16), 256, 0, stream>>>(Vb, Vfr);
    k_attn<<<2048, 128, 0, stream>>>(Qb, Kfr, Vfr, Ob);
    k_gemm_out<<<dim3(8, 32), 256, 0, stream>>>(Ob, WoT, bo, out);
}

// Round 13
// 151.277 us; speedup vs baseline: 1.5553x; 1.0674x over previous
//
#include <hip/hip_runtime.h>

typedef __bf16 bf16;
typedef __bf16 bf16x8 __attribute__((ext_vector_type(8)));
typedef float f32x4 __attribute__((ext_vector_type(4)));
typedef float f32x16 __attribute__((ext_vector_type(16)));
typedef unsigned u32x2 __attribute__((ext_vector_type(2)));

#define MFMA16(a, b, c) __builtin_amdgcn_mfma_f32_16x16x32_bf16((a), (b), (c), 0, 0, 0)
#define MFMA32(a, b, c) __builtin_amdgcn_mfma_f32_32x32x16_bf16((a), (b), (c), 0, 0, 0)

typedef const __attribute__((address_space(1))) uint32_t glb_u32;
typedef __attribute__((address_space(3))) uint32_t lds_u32;
#define GLOAD16(gp, lp) __builtin_amdgcn_global_load_lds((glb_u32*)(gp), (lds_u32*)(lp), 16, 0, 0)

// ---------------- elementwise f32 -> bf16 (8 per thread) ----------------
__global__ __launch_bounds__(256) void k_convX(const float* __restrict__ in, bf16* __restrict__ out) {
    size_t i = ((size_t)blockIdx.x * 256 + threadIdx.x) * 8;
    float4 a = *(const float4*)(in + i);
    float4 b = *(const float4*)(in + i + 4);
    bf16 e[8];
    e[0] = (bf16)a.x; e[1] = (bf16)a.y; e[2] = (bf16)a.z; e[3] = (bf16)a.w;
    e[4] = (bf16)b.x; e[5] = (bf16)b.y; e[6] = (bf16)b.z; e[7] = (bf16)b.w;
    uint4 u; __builtin_memcpy(&u, e, 16);
    *(uint4*)(out + i) = u;
}

// ------------- transpose+convert: in f32 [R][C] -> out bf16 [C][R] -------------
__global__ __launch_bounds__(256) void k_tconv(const float* __restrict__ in, bf16* __restrict__ out,
                                               int R, int C) {
    __shared__ float tile[64][65];
    int bx = blockIdx.x, by = blockIdx.y;
    int t = threadIdx.x;
    for (int i = 0; i < 16; ++i) {
        int e = i * 256 + t; int r = e >> 6, c = e & 63;
        tile[r][c] = in[(size_t)(by * 64 + r) * C + bx * 64 + c];
    }
    __syncthreads();
    for (int i = 0; i < 16; ++i) {
        int e = i * 256 + t; int r = e >> 6, c = e & 63;
        out[(size_t)(bx * 64 + r) * R + by * 64 + c] = (bf16)tile[c][r];
    }
}

// ------------- 128x128 bf16 GEMM core -------------
__device__ __forceinline__ void gemm128_core(const bf16* __restrict__ A, const bf16* __restrict__ Bt,
                                             int r0, int c0, int Kd, char* As, char* Bs,
                                             f32x4 (&acc)[4][4]) {
    int t = threadIdx.x, l = t & 63, w = t >> 6;
    int g = l >> 4, li = l & 15;
    int wr = w >> 1, wc = w & 1;
    for (int k0 = 0; k0 < Kd; k0 += 64) {
        __syncthreads();
        #pragma unroll
        for (int i = 0; i < 4; ++i) {
            int slot = i * 256 + t;
            int row = slot >> 3;
            int ch  = (slot & 7) ^ (row & 7);
            int base = (i * 256 + w * 64) * 16;
            GLOAD16(A  + (size_t)(r0 + row) * Kd + k0 + ch * 8, As + base);
            GLOAD16(Bt + (size_t)(c0 + row) * Kd + k0 + ch * 8, Bs + base);
        }
        __syncthreads();
        __builtin_amdgcn_s_setprio(1);
        #pragma unroll
        for (int kk = 0; kk < 2; ++kk) {
            bf16x8 af[4], bfr[4];
            #pragma unroll
            for (int m = 0; m < 4; ++m) {
                int row = wr * 64 + m * 16 + li;
                af[m] = *(const bf16x8*)(As + ((row * 128 + kk * 64 + g * 16) ^ ((row & 7) << 4)));
            }
            #pragma unroll
            for (int n = 0; n < 4; ++n) {
                int row = wc * 64 + n * 16 + li;
                bfr[n] = *(const bf16x8*)(Bs + ((row * 128 + kk * 64 + g * 16) ^ ((row & 7) << 4)));
            }
            #pragma unroll
            for (int m = 0; m < 4; ++m)
                #pragma unroll
                for (int n = 0; n < 4; ++n)
                    acc[m][n] = MFMA16(af[m], bfr[n], acc[m][n]);
        }
        __builtin_amdgcn_s_setprio(0);
    }
}

// ------------- GEMM1: qkv = Xb @ WqkvT^T + bqkv; epilogue writes Q row-major (scaled)
//               and K/V directly in FRAG-PACKED layout (fuses old k_kpack/k_vtrans) -----------
__global__ __launch_bounds__(256) void k_gemm_qkv(const bf16* __restrict__ Xb, const bf16* __restrict__ WqkvT,
                                                  const float* __restrict__ bqkv,
                                                  bf16* __restrict__ Q, bf16* __restrict__ Kfr,
                                                  bf16* __restrict__ Vfr) {
    __shared__ __align__(16) char As[16384];
    __shared__ __align__(16) char Bs[16384];
    int r0 = blockIdx.y * 128, c0 = blockIdx.x * 128;
    f32x4 acc[4][4] = {};
    gemm128_core(Xb, WqkvT, r0, c0, 1024, As, Bs, acc);
    int t = threadIdx.x, l = t & 63, w = t >> 6;
    int g = l >> 4, li = l & 15;
    int wr = w >> 1, wc = w & 1;
    int colbase = c0 + wc * 64;            // one head per wave-column
    int sec = colbase >> 10;               // 0=Q 1=K 2=V
    int head = (colbase & 1023) >> 6;
    if (sec == 0) {
        // Q carries 1/sqrt(64) * log2(e) so attention softmax runs in exp2 domain
        const float scale = 0.125f * 1.44269504f;
        #pragma unroll
        for (int m = 0; m < 4; ++m)
            #pragma unroll
            for (int n = 0; n < 4; ++n) {
                int hd = n * 16 + li;
                float bias = bqkv[colbase + hd];
                #pragma unroll
                for (int r = 0; r < 4; ++r) {
                    int row = r0 + wr * 64 + m * 16 + g * 4 + r;
                    Q[(size_t)(head * 4096 + row) * 64 + hd] = (bf16)((acc[m][n][r] + bias) * scale);
                }
            }
    } else if (sec == 1) {
        // K frag layout: elem K[t][hd] -> chunk (t>>5)*256 + (hd>>4)*64 + (t&31) + 32*((hd>>3)&1),
        // byte elem hd&7.  addr(r) linear: +8 elems per r.
        bf16* dstK = Kfr + (size_t)head * 262144;
        #pragma unroll
        for (int m = 0; m < 4; ++m) {
            int tbase = r0 + wr * 64 + m * 16 + g * 4;
            size_t tpart = (size_t)(tbase >> 5) * 2048 + (size_t)(tbase & 31) * 8;
            #pragma unroll
            for (int n = 0; n < 4; ++n) {
                int hd = n * 16 + li;
                float bias = bqkv[colbase + hd];
                size_t A0 = tpart + (size_t)(hd >> 4) * 512 + (size_t)((hd >> 3) & 1) * 256 + (hd & 7);
                #pragma unroll
                for (int r = 0; r < 4; ++r)
                    dstK[A0 + (size_t)r * 8] = (bf16)(acc[m][n][r] + bias);
            }
        }
    } else {
        // V frag layout: elem V[t][d] -> chunk (t>>5)*256 + ((d>>5)*2+((t>>4)&1))*64 + (d&31)
        //                + 32*((t>>3)&1), byte elem t&7.  addr(r) = A0 + r -> one 8B store.
        bf16* dstV = Vfr + (size_t)head * 262144;
        #pragma unroll
        for (int m = 0; m < 4; ++m) {
            int tbase = r0 + wr * 64 + m * 16 + g * 4;
            size_t tpart = (size_t)(tbase >> 5) * 2048 + (size_t)((tbase >> 4) & 1) * 512
                         + (size_t)((tbase >> 3) & 1) * 256 + (tbase & 7);
            #pragma unroll
            for (int n = 0; n < 4; ++n) {
                int hd = n * 16 + li;
                float bias = bqkv[colbase + hd];
                size_t A0 = tpart + (size_t)(hd >> 5) * 1024 + (size_t)(hd & 31) * 8;
                bf16 e4[4];
                #pragma unroll
                for (int r = 0; r < 4; ++r) e4[r] = (bf16)(acc[m][n][r] + bias);
                unsigned long long pk; __builtin_memcpy(&pk, e4, 8);
                *(unsigned long long*)(dstV + A0) = pk;
            }
        }
    }
}

// ------------- GEMM2: out = Ob @ WoT^T + bo (f32 out), 128x64 tiles for 2 blocks/CU ----------
__global__ __launch_bounds__(256) void k_gemm_out(const bf16* __restrict__ Ob, const bf16* __restrict__ WoT,
                                                  const float* __restrict__ bo, float* __restrict__ out) {
    __shared__ __align__(16) char As[16384];   // 128 rows x 128B
    __shared__ __align__(16) char Bs[8192];    //  64 rows x 128B
    int r0 = blockIdx.y * 128, c0 = blockIdx.x * 64;
    int t = threadIdx.x, l = t & 63, w = t >> 6;
    int g = l >> 4, li = l & 15;
    f32x4 acc[2][4] = {};
    for (int k0 = 0; k0 < 1024; k0 += 64) {
        __syncthreads();
        #pragma unroll
        for (int i = 0; i < 4; ++i) {
            int slot = i * 256 + t;
            int row = slot >> 3;
            int ch  = (slot & 7) ^ (row & 7);
            int base = (i * 256 + w * 64) * 16;
            GLOAD16(Ob + (size_t)(r0 + row) * 1024 + k0 + ch * 8, As + base);
        }
        #pragma unroll
        for (int i = 0; i < 2; ++i) {
            int slot = i * 256 + t;
            int row = slot >> 3;
            int ch  = (slot & 7) ^ (row & 7);
            int base = (i * 256 + w * 64) * 16;
            GLOAD16(WoT + (size_t)(c0 + row) * 1024 + k0 + ch * 8, Bs + base);
        }
        __syncthreads();
        __builtin_amdgcn_s_setprio(1);
        #pragma unroll
        for (int kk = 0; kk < 2; ++kk) {
            bf16x8 af[2], bfr[4];
            #pragma unroll
            for (int m = 0; m < 2; ++m) {
                int row = w * 32 + m * 16 + li;
                af[m] = *(const bf16x8*)(As + ((row * 128 + kk * 64 + g * 16) ^ ((row & 7) << 4)));
            }
            #pragma unroll
            for (int n = 0; n < 4; ++n) {
                int row = n * 16 + li;
                bfr[n] = *(const bf16x8*)(Bs + ((row * 128 + kk * 64 + g * 16) ^ ((row & 7) << 4)));
            }
            #pragma unroll
            for (int m = 0; m < 2; ++m)
                #pragma unroll
                for (int n = 0; n < 4; ++n)
                    acc[m][n] = MFMA16(af[m], bfr[n], acc[m][n]);
        }
        __builtin_amdgcn_s_setprio(0);
    }
    #pragma unroll
    for (int m = 0; m < 2; ++m)
        #pragma unroll
        for (int n = 0; n < 4; ++n) {
            int col = c0 + n * 16 + li;
            float bias = bo[col];
            #pragma unroll
            for (int r = 0; r < 4; ++r) {
                int row = r0 + w * 32 + m * 16 + g * 4 + r;
                out[(size_t)row * 1024 + col] = acc[m][n][r] + bias;
            }
        }
}

// pack two f32 -> u32 of two bf16
__device__ __forceinline__ unsigned pkbf(float a, float b) {
    bf16 h0 = (bf16)a, h1 = (bf16)b;
    unsigned short u0, u1;
    __builtin_memcpy(&u0, &h0, 2); __builtin_memcpy(&u1, &h1, 2);
    return (unsigned)u0 | ((unsigned)u1 << 16);
}

// ------------- causal flash attention, swapped-QK 32x32, register-direct K/V (R12 best) -------
__global__ __launch_bounds__(128) void k_attn(const bf16* __restrict__ Q, const uint4* __restrict__ Kfr,
                                              const uint4* __restrict__ Vfr, bf16* __restrict__ O) {
    __shared__ float Op[32][64];      // wave1 partial O [q][d]
    __shared__ float Ml[2][32];       // wave1 partial {m,l}[q]
    int bid = blockIdx.x;
    int h = bid & 15;                 // h%8 == bid%8 -> XCD head affinity
    int u = bid >> 4;                 // 0..127
    int jj = (u < 64) ? u : 191 - u;  // per-CU balanced q-tile index
    int w = threadIdx.x >> 6;
    int l = threadIdx.x & 63;
    int lc = l & 31, hi = l >> 5;
    int hi4 = hi * 4, hi8 = hi * 8;
    const bf16* Qh = Q + (size_t)h * 4096 * 64;
    const uint4* Kh = Kfr + (size_t)h * 32768;
    const uint4* Vh = Vfr + (size_t)h * 32768;
    int nt = jj + 1;
    int hA = (nt + 1) >> 1;
    int tb = w ? hA : 0;
    int te = w ? nt : hA;

    f32x16 oacc[2] = {};
    float m = -1e30f, lsum = 0.f;
    uint4 kA[4], vA[4], kB[4], vB[4];
    bf16x8 qf[4];
    #pragma unroll
    for (int kst = 0; kst < 4; ++kst)
        qf[kst] = *(const bf16x8*)(Qh + (size_t)(jj * 32 + lc) * 64 + kst * 16 + hi8);

    auto compute = [&](int tt, uint4 (&kf)[4], uint4 (&vf)[4]) {
        f32x16 sacc = {};
        __builtin_amdgcn_s_setprio(1);
        #pragma unroll
        for (int kst = 0; kst < 4; ++kst) {
            bf16x8 kk; __builtin_memcpy(&kk, &kf[kst], 16);
            sacc = MFMA32(kk, qf[kst], sacc);
        }
        __builtin_amdgcn_s_setprio(0);
        if (tt == jj) {
            #pragma unroll
            for (int r = 0; r < 16; ++r) {
                int tloc = (r & 3) + 8 * (r >> 2) + hi4;
                if (tloc > lc) sacc[r] = -1e30f;
            }
        }
        float t8[8];
        #pragma unroll
        for (int r = 0; r < 8; ++r) t8[r] = fmaxf(sacc[r], sacc[r + 8]);
        float ta = fmaxf(fmaxf(t8[0], t8[1]), t8[2]);
        float tb3 = fmaxf(fmaxf(t8[3], t8[4]), t8[5]);
        float tc = fmaxf(t8[6], t8[7]);
        float pm = fmaxf(fmaxf(ta, tb3), tc);
        pm = fmaxf(pm, __shfl_xor(pm, 32));
        if (!__all(pm - m <= 8.0f)) {
            float mn = fmaxf(m, pm);
            float al = exp2f(m - mn);
            #pragma unroll
            for (int r = 0; r < 16; ++r) {
                int ql = (r & 3) + 8 * (r >> 2) + hi4;
                float alb = __shfl(al, ql);
                oacc[0][r] *= alb;
                oacc[1][r] *= alb;
            }
            lsum *= al;
            m = mn;
        }
        float pv[16];
        float rs0 = 0.f, rs1 = 0.f;
        #pragma unroll
        for (int r = 0; r < 8; ++r) {
            pv[r]     = exp2f(sacc[r] - m);     rs0 += pv[r];
            pv[r + 8] = exp2f(sacc[r + 8] - m); rs1 += pv[r + 8];
        }
        lsum += rs0 + rs1;
        #pragma unroll
        for (int ks = 0; ks < 2; ++ks) {
            int b = ks * 8;
            unsigned a0 = pkbf(pv[b + 0], pv[b + 1]), a1 = pkbf(pv[b + 2], pv[b + 3]);
            unsigned b0 = pkbf(pv[b + 4], pv[b + 5]), b1 = pkbf(pv[b + 6], pv[b + 7]);
            u32x2 r0 = __builtin_amdgcn_permlane32_swap(a0, b0, false, false);
            u32x2 r1 = __builtin_amdgcn_permlane32_swap(a1, b1, false, false);
            unsigned wsq[4] = { r0[0], r1[0], r0[1], r1[1] };
            bf16x8 pa; __builtin_memcpy(&pa, wsq, 16);
            __builtin_amdgcn_s_setprio(1);
            #pragma unroll
            for (int jt = 0; jt < 2; ++jt) {
                bf16x8 vv; __builtin_memcpy(&vv, &vf[jt * 2 + ks], 16);
                oacc[jt] = MFMA32(pa, vv, oacc[jt]);
            }
            __builtin_amdgcn_s_setprio(0);
        }
    };

    if (te > tb) {
        #pragma unroll
        for (int i = 0; i < 4; ++i) {
            kA[i] = Kh[(size_t)tb * 256 + i * 64 + l];
            vA[i] = Vh[(size_t)tb * 256 + i * 64 + l];
        }
        int i = tb;
        for (; i + 2 <= te; i += 2) {
            const uint4* Kn = Kh + (size_t)(i + 1) * 256;
            const uint4* Vn = Vh + (size_t)(i + 1) * 256;
            #pragma unroll
            for (int q = 0; q < 4; ++q) { kB[q] = Kn[q * 64 + l]; vB[q] = Vn[q * 64 + l]; }
            compute(i, kA, vA);
            if (i + 2 < te) {
                const uint4* K2 = Kh + (size_t)(i + 2) * 256;
                const uint4* V2 = Vh + (size_t)(i + 2) * 256;
                #pragma unroll
                for (int q = 0; q < 4; ++q) { kA[q] = K2[q * 64 + l]; vA[q] = V2[q * 64 + l]; }
            }
            compute(i + 1, kB, vB);
        }
        if ((te - tb) & 1) compute(te - 1, kA, vA);
    }
    lsum += __shfl_xor(lsum, 32);

    if (w == 1) {
        #pragma unroll
        for (int r = 0; r < 16; ++r) {
            int ql = (r & 3) + 8 * (r >> 2) + hi4;
            Op[ql][lc]      = oacc[0][r];
            Op[ql][32 + lc] = oacc[1][r];
        }
        if (hi == 0) { Ml[0][lc] = m; Ml[1][lc] = lsum; }
    }
    __syncthreads();
    if (w == 0) {
        float mo = Ml[0][lc], lo = Ml[1][lc];
        float mm = fmaxf(m, mo);
        float alr = exp2f(m - mm), alo = exp2f(mo - mm);
        float lf = lsum * alr + lo * alo;
        float inv = 1.0f / lf;
        float fr = alr * inv, fo = alo * inv;
        int q0 = jj * 32;
        #pragma unroll
        for (int r = 0; r < 16; ++r) {
            int ql = (r & 3) + 8 * (r >> 2) + hi4;
            float frb = __shfl(fr, ql), fob = __shfl(fo, ql);
            float o0 = oacc[0][r] * frb + Op[ql][lc]      * fob;
            float o1 = oacc[1][r] * frb + Op[ql][32 + lc] * fob;
            int row = q0 + ql;
            O[(size_t)row * 1024 + h * 64 + lc]      = (bf16)o0;
            O[(size_t)row * 1024 + h * 64 + 32 + lc] = (bf16)o1;
        }
    }
}

extern "C" void kernel_launch(void* const* d_in, const int* in_sizes, int n_in,
                              void* d_out, int out_size, void* d_ws, size_t ws_size,
                              hipStream_t stream) {
    const float* X    = (const float*)d_in[0];   // [1,4096,1024]
    const float* Wqkv = (const float*)d_in[1];   // [1024,3072]
    const float* bqkv = (const float*)d_in[2];   // [3072]
    const float* Wo   = (const float*)d_in[3];   // [1024,1024]
    const float* bo   = (const float*)d_in[4];   // [1024]
    float* out = (float*)d_out;

    char* ws = (char*)d_ws;
    const size_t MB = 1024 * 1024;
    bf16*  Xb    = (bf16*)(ws);             //  8 MB [4096][1024]; dead after gemm_qkv
    bf16*  WqkvT = (bf16*)(ws + 8  * MB);   //  6 MB [3072][1024]
    bf16*  WoT   = (bf16*)(ws + 14 * MB);   //  2 MB [1024][1024]
    bf16*  Qb    = (bf16*)(ws + 16 * MB);   //  8 MB [16][4096][64]
    uint4* Kfr   = (uint4*)(ws + 40 * MB);  //  8 MB frag-packed K (written by gemm_qkv)
    uint4* Vfr   = (uint4*)(ws + 48 * MB);  //  8 MB frag-packed V^T (written by gemm_qkv)
    bf16*  Ob    = Xb;                      //  alias: Xb dead before attn writes Ob

    k_convX<<<2048, 256, 0, stream>>>(X, Xb);
    k_tconv<<<dim3(48, 16), 256, 0, stream>>>(Wqkv, WqkvT, 1024, 3072);
    k_tconv<<<dim3(16, 16), 256, 0, stream>>>(Wo, WoT, 1024, 1024);
    k_gemm_qkv<<<dim3(24, 32), 256, 0, stream>>>(Xb, WqkvT, bqkv, Qb, (bf16*)Kfr, (bf16*)Vfr);
    k_attn<<<2048, 128, 0, stream>>>(Qb, Kfr, Vfr, Ob);
    k_gemm_out<<<dim3(16, 32), 256, 0, stream>>>(Ob, WoT, bo, out);
}

// Round 14
// 147.757 us; speedup vs baseline: 1.5924x; 1.0238x over previous
//
#include <hip/hip_runtime.h>

typedef __bf16 bf16;
typedef __bf16 bf16x8 __attribute__((ext_vector_type(8)));
typedef float f32x4 __attribute__((ext_vector_type(4)));
typedef float f32x16 __attribute__((ext_vector_type(16)));
typedef unsigned u32x2 __attribute__((ext_vector_type(2)));

#define MFMA16(a, b, c) __builtin_amdgcn_mfma_f32_16x16x32_bf16((a), (b), (c), 0, 0, 0)
#define MFMA32(a, b, c) __builtin_amdgcn_mfma_f32_32x32x16_bf16((a), (b), (c), 0, 0, 0)

typedef const __attribute__((address_space(1))) uint32_t glb_u32;
typedef __attribute__((address_space(3))) uint32_t lds_u32;
#define GLOAD16(gp, lp) __builtin_amdgcn_global_load_lds((glb_u32*)(gp), (lds_u32*)(lp), 16, 0, 0)

// ------------- fused prep: X f32->bf16 copy, Wqkv^T, Wo^T (one launch) -------------
__global__ __launch_bounds__(256) void k_prep(const float* __restrict__ X, bf16* __restrict__ Xb,
                                              const float* __restrict__ Wqkv, bf16* __restrict__ WqkvT,
                                              const float* __restrict__ Wo, bf16* __restrict__ WoT) {
    __shared__ float tile[64][65];
    int bid = blockIdx.x;
    int t = threadIdx.x;
    if (bid < 2048) {
        size_t i = ((size_t)bid * 256 + t) * 8;
        float4 a = *(const float4*)(X + i);
        float4 b = *(const float4*)(X + i + 4);
        bf16 e[8];
        e[0] = (bf16)a.x; e[1] = (bf16)a.y; e[2] = (bf16)a.z; e[3] = (bf16)a.w;
        e[4] = (bf16)b.x; e[5] = (bf16)b.y; e[6] = (bf16)b.z; e[7] = (bf16)b.w;
        uint4 u; __builtin_memcpy(&u, e, 16);
        *(uint4*)(Xb + i) = u;
        return;
    }
    const float* in; bf16* out; int R, C, bx, by;
    if (bid < 2816) {
        in = Wqkv; out = WqkvT; R = 1024; C = 3072;
        int b = bid - 2048; bx = b % 48; by = b / 48;      // 48 x 16
    } else {
        in = Wo; out = WoT; R = 1024; C = 1024;
        int b = bid - 2816; bx = b & 15; by = b >> 4;      // 16 x 16
    }
    for (int i = 0; i < 16; ++i) {
        int e = i * 256 + t; int r = e >> 6, c = e & 63;
        tile[r][c] = in[(size_t)(by * 64 + r) * C + bx * 64 + c];
    }
    __syncthreads();
    for (int i = 0; i < 16; ++i) {
        int e = i * 256 + t; int r = e >> 6, c = e & 63;
        out[(size_t)(bx * 64 + r) * R + by * 64 + c] = (bf16)tile[c][r];
    }
}

// ------------- 128x128 bf16 GEMM core -------------
__device__ __forceinline__ void gemm128_core(const bf16* __restrict__ A, const bf16* __restrict__ Bt,
                                             int r0, int c0, int Kd, char* As, char* Bs,
                                             f32x4 (&acc)[4][4]) {
    int t = threadIdx.x, l = t & 63, w = t >> 6;
    int g = l >> 4, li = l & 15;
    int wr = w >> 1, wc = w & 1;
    for (int k0 = 0; k0 < Kd; k0 += 64) {
        __syncthreads();
        #pragma unroll
        for (int i = 0; i < 4; ++i) {
            int slot = i * 256 + t;
            int row = slot >> 3;
            int ch  = (slot & 7) ^ (row & 7);
            int base = (i * 256 + w * 64) * 16;
            GLOAD16(A  + (size_t)(r0 + row) * Kd + k0 + ch * 8, As + base);
            GLOAD16(Bt + (size_t)(c0 + row) * Kd + k0 + ch * 8, Bs + base);
        }
        __syncthreads();
        __builtin_amdgcn_s_setprio(1);
        #pragma unroll
        for (int kk = 0; kk < 2; ++kk) {
            bf16x8 af[4], bfr[4];
            #pragma unroll
            for (int m = 0; m < 4; ++m) {
                int row = wr * 64 + m * 16 + li;
                af[m] = *(const bf16x8*)(As + ((row * 128 + kk * 64 + g * 16) ^ ((row & 7) << 4)));
            }
            #pragma unroll
            for (int n = 0; n < 4; ++n) {
                int row = wc * 64 + n * 16 + li;
                bfr[n] = *(const bf16x8*)(Bs + ((row * 128 + kk * 64 + g * 16) ^ ((row & 7) << 4)));
            }
            #pragma unroll
            for (int m = 0; m < 4; ++m)
                #pragma unroll
                for (int n = 0; n < 4; ++n)
                    acc[m][n] = MFMA16(af[m], bfr[n], acc[m][n]);
        }
        __builtin_amdgcn_s_setprio(0);
    }
}

// ------------- GEMM1: qkv = Xb @ WqkvT^T + bqkv; Q row-major (scaled), K/V frag-packed ----------
// 1D grid 768, bijective XCD swizzle (m204): L=(bid&7)*96+(bid>>3), by-major chunks per XCD.
__global__ __launch_bounds__(256) void k_gemm_qkv(const bf16* __restrict__ Xb, const bf16* __restrict__ WqkvT,
                                                  const float* __restrict__ bqkv,
                                                  bf16* __restrict__ Q, bf16* __restrict__ Kfr,
                                                  bf16* __restrict__ Vfr) {
    __shared__ __align__(16) char As[16384];
    __shared__ __align__(16) char Bs[16384];
    int bid = blockIdx.x;
    int Lg = (bid & 7) * 96 + (bid >> 3);
    int bx = Lg % 24, by = Lg / 24;
    int r0 = by * 128, c0 = bx * 128;
    f32x4 acc[4][4] = {};
    gemm128_core(Xb, WqkvT, r0, c0, 1024, As, Bs, acc);
    int t = threadIdx.x, l = t & 63, w = t >> 6;
    int g = l >> 4, li = l & 15;
    int wr = w >> 1, wc = w & 1;
    int colbase = c0 + wc * 64;            // one head per wave-column
    int sec = colbase >> 10;               // 0=Q 1=K 2=V
    int head = (colbase & 1023) >> 6;
    if (sec == 0) {
        // Q carries 1/sqrt(64) * log2(e) so attention softmax runs in exp2 domain
        const float scale = 0.125f * 1.44269504f;
        #pragma unroll
        for (int m = 0; m < 4; ++m)
            #pragma unroll
            for (int n = 0; n < 4; ++n) {
                int hd = n * 16 + li;
                float bias = bqkv[colbase + hd];
                #pragma unroll
                for (int r = 0; r < 4; ++r) {
                    int row = r0 + wr * 64 + m * 16 + g * 4 + r;
                    Q[(size_t)(head * 4096 + row) * 64 + hd] = (bf16)((acc[m][n][r] + bias) * scale);
                }
            }
    } else if (sec == 1) {
        // K frag layout: elem K[t][hd] -> chunk (t>>5)*256 + (hd>>4)*64 + (t&31) + 32*((hd>>3)&1),
        // byte elem hd&7.  addr(r) linear: +8 elems per r.
        bf16* dstK = Kfr + (size_t)head * 262144;
        #pragma unroll
        for (int m = 0; m < 4; ++m) {
            int tbase = r0 + wr * 64 + m * 16 + g * 4;
            size_t tpart = (size_t)(tbase >> 5) * 2048 + (size_t)(tbase & 31) * 8;
            #pragma unroll
            for (int n = 0; n < 4; ++n) {
                int hd = n * 16 + li;
                float bias = bqkv[colbase + hd];
                size_t A0 = tpart + (size_t)(hd >> 4) * 512 + (size_t)((hd >> 3) & 1) * 256 + (hd & 7);
                #pragma unroll
                for (int r = 0; r < 4; ++r)
                    dstK[A0 + (size_t)r * 8] = (bf16)(acc[m][n][r] + bias);
            }
        }
    } else {
        // V frag layout: elem V[t][d] -> chunk (t>>5)*256 + ((d>>5)*2+((t>>4)&1))*64 + (d&31)
        //                + 32*((t>>3)&1), byte elem t&7.  addr(r) = A0 + r -> one 8B store.
        bf16* dstV = Vfr + (size_t)head * 262144;
        #pragma unroll
        for (int m = 0; m < 4; ++m) {
            int tbase = r0 + wr * 64 + m * 16 + g * 4;
            size_t tpart = (size_t)(tbase >> 5) * 2048 + (size_t)((tbase >> 4) & 1) * 512
                         + (size_t)((tbase >> 3) & 1) * 256 + (tbase & 7);
            #pragma unroll
            for (int n = 0; n < 4; ++n) {
                int hd = n * 16 + li;
                float bias = bqkv[colbase + hd];
                size_t A0 = tpart + (size_t)(hd >> 5) * 1024 + (size_t)(hd & 31) * 8;
                bf16 e4[4];
                #pragma unroll
                for (int r = 0; r < 4; ++r) e4[r] = (bf16)(acc[m][n][r] + bias);
                unsigned long long pk; __builtin_memcpy(&pk, e4, 8);
                *(unsigned long long*)(dstV + A0) = pk;
            }
        }
    }
}

// ------------- GEMM2: out = Ob @ WoT^T + bo (f32 out), 128x64 tiles, XCD swizzle ----------
__global__ __launch_bounds__(256) void k_gemm_out(const bf16* __restrict__ Ob, const bf16* __restrict__ WoT,
                                                  const float* __restrict__ bo, float* __restrict__ out) {
    __shared__ __align__(16) char As[16384];   // 128 rows x 128B
    __shared__ __align__(16) char Bs[8192];    //  64 rows x 128B
    int bid = blockIdx.x;
    int Lg = (bid & 7) * 64 + (bid >> 3);      // 512 blocks, bijective
    int bx = Lg & 15, by = Lg >> 4;
    int r0 = by * 128, c0 = bx * 64;
    int t = threadIdx.x, l = t & 63, w = t >> 6;
    int g = l >> 4, li = l & 15;
    f32x4 acc[2][4] = {};
    for (int k0 = 0; k0 < 1024; k0 += 64) {
        __syncthreads();
        #pragma unroll
        for (int i = 0; i < 4; ++i) {
            int slot = i * 256 + t;
            int row = slot >> 3;
            int ch  = (slot & 7) ^ (row & 7);
            int base = (i * 256 + w * 64) * 16;
            GLOAD16(Ob + (size_t)(r0 + row) * 1024 + k0 + ch * 8, As + base);
        }
        #pragma unroll
        for (int i = 0; i < 2; ++i) {
            int slot = i * 256 + t;
            int row = slot >> 3;
            int ch  = (slot & 7) ^ (row & 7);
            int base = (i * 256 + w * 64) * 16;
            GLOAD16(WoT + (size_t)(c0 + row) * 1024 + k0 + ch * 8, Bs + base);
        }
        __syncthreads();
        __builtin_amdgcn_s_setprio(1);
        #pragma unroll
        for (int kk = 0; kk < 2; ++kk) {
            bf16x8 af[2], bfr[4];
            #pragma unroll
            for (int m = 0; m < 2; ++m) {
                int row = w * 32 + m * 16 + li;
                af[m] = *(const bf16x8*)(As + ((row * 128 + kk * 64 + g * 16) ^ ((row & 7) << 4)));
            }
            #pragma unroll
            for (int n = 0; n < 4; ++n) {
                int row = n * 16 + li;
                bfr[n] = *(const bf16x8*)(Bs + ((row * 128 + kk * 64 + g * 16) ^ ((row & 7) << 4)));
            }
            #pragma unroll
            for (int m = 0; m < 2; ++m)
                #pragma unroll
                for (int n = 0; n < 4; ++n)
                    acc[m][n] = MFMA16(af[m], bfr[n], acc[m][n]);
        }
        __builtin_amdgcn_s_setprio(0);
    }
    #pragma unroll
    for (int m = 0; m < 2; ++m)
        #pragma unroll
        for (int n = 0; n < 4; ++n) {
            int col = c0 + n * 16 + li;
            float bias = bo[col];
            #pragma unroll
            for (int r = 0; r < 4; ++r) {
                int row = r0 + w * 32 + m * 16 + g * 4 + r;
                out[(size_t)row * 1024 + col] = acc[m][n][r] + bias;
            }
        }
}

// pack two f32 -> u32 of two bf16
__device__ __forceinline__ unsigned pkbf(float a, float b) {
    bf16 h0 = (bf16)a, h1 = (bf16)b;
    unsigned short u0, u1;
    __builtin_memcpy(&u0, &h0, 2); __builtin_memcpy(&u1, &h1, 2);
    return (unsigned)u0 | ((unsigned)u1 << 16);
}

// ------------- causal flash attention, swapped-QK 32x32, register-direct K/V (R12 best) -------
__global__ __launch_bounds__(128) void k_attn(const bf16* __restrict__ Q, const uint4* __restrict__ Kfr,
                                              const uint4* __restrict__ Vfr, bf16* __restrict__ O) {
    __shared__ float Op[32][64];      // wave1 partial O [q][d]
    __shared__ float Ml[2][32];       // wave1 partial {m,l}[q]
    int bid = blockIdx.x;
    int h = bid & 15;                 // h%8 == bid%8 -> XCD head affinity
    int u = bid >> 4;                 // 0..127
    int jj = (u < 64) ? u : 191 - u;  // per-CU balanced q-tile index
    int w = threadIdx.x >> 6;
    int l = threadIdx.x & 63;
    int lc = l & 31, hi = l >> 5;
    int hi4 = hi * 4, hi8 = hi * 8;
    const bf16* Qh = Q + (size_t)h * 4096 * 64;
    const uint4* Kh = Kfr + (size_t)h * 32768;
    const uint4* Vh = Vfr + (size_t)h * 32768;
    int nt = jj + 1;
    int hA = (nt + 1) >> 1;
    int tb = w ? hA : 0;
    int te = w ? nt : hA;

    f32x16 oacc[2] = {};
    float m = -1e30f, lsum = 0.f;
    uint4 kA[4], vA[4], kB[4], vB[4];
    bf16x8 qf[4];
    #pragma unroll
    for (int kst = 0; kst < 4; ++kst)
        qf[kst] = *(const bf16x8*)(Qh + (size_t)(jj * 32 + lc) * 64 + kst * 16 + hi8);

    auto compute = [&](int tt, uint4 (&kf)[4], uint4 (&vf)[4]) {
        f32x16 sacc = {};
        __builtin_amdgcn_s_setprio(1);
        #pragma unroll
        for (int kst = 0; kst < 4; ++kst) {
            bf16x8 kk; __builtin_memcpy(&kk, &kf[kst], 16);
            sacc = MFMA32(kk, qf[kst], sacc);
        }
        __builtin_amdgcn_s_setprio(0);
        if (tt == jj) {
            #pragma unroll
            for (int r = 0; r < 16; ++r) {
                int tloc = (r & 3) + 8 * (r >> 2) + hi4;
                if (tloc > lc) sacc[r] = -1e30f;
            }
        }
        float t8[8];
        #pragma unroll
        for (int r = 0; r < 8; ++r) t8[r] = fmaxf(sacc[r], sacc[r + 8]);
        float ta = fmaxf(fmaxf(t8[0], t8[1]), t8[2]);
        float tb3 = fmaxf(fmaxf(t8[3], t8[4]), t8[5]);
        float tc = fmaxf(t8[6], t8[7]);
        float pm = fmaxf(fmaxf(ta, tb3), tc);
        pm = fmaxf(pm, __shfl_xor(pm, 32));
        if (!__all(pm - m <= 8.0f)) {
            float mn = fmaxf(m, pm);
            float al = exp2f(m - mn);
            #pragma unroll
            for (int r = 0; r < 16; ++r) {
                int ql = (r & 3) + 8 * (r >> 2) + hi4;
                float alb = __shfl(al, ql);
                oacc[0][r] *= alb;
                oacc[1][r] *= alb;
            }
            lsum *= al;
            m = mn;
        }
        float pv[16];
        float rs0 = 0.f, rs1 = 0.f;
        #pragma unroll
        for (int r = 0; r < 8; ++r) {
            pv[r]     = exp2f(sacc[r] - m);     rs0 += pv[r];
            pv[r + 8] = exp2f(sacc[r + 8] - m); rs1 += pv[r + 8];
        }
        lsum += rs0 + rs1;
        #pragma unroll
        for (int ks = 0; ks < 2; ++ks) {
            int b = ks * 8;
            unsigned a0 = pkbf(pv[b + 0], pv[b + 1]), a1 = pkbf(pv[b + 2], pv[b + 3]);
            unsigned b0 = pkbf(pv[b + 4], pv[b + 5]), b1 = pkbf(pv[b + 6], pv[b + 7]);
            u32x2 r0 = __builtin_amdgcn_permlane32_swap(a0, b0, false, false);
            u32x2 r1 = __builtin_amdgcn_permlane32_swap(a1, b1, false, false);
            unsigned wsq[4] = { r0[0], r1[0], r0[1], r1[1] };
            bf16x8 pa; __builtin_memcpy(&pa, wsq, 16);
            __builtin_amdgcn_s_setprio(1);
            #pragma unroll
            for (int jt = 0; jt < 2; ++jt) {
                bf16x8 vv; __builtin_memcpy(&vv, &vf[jt * 2 + ks], 16);
                oacc[jt] = MFMA32(pa, vv, oacc[jt]);
            }
            __builtin_amdgcn_s_setprio(0);
        }
    };

    if (te > tb) {
        #pragma unroll
        for (int i = 0; i < 4; ++i) {
            kA[i] = Kh[(size_t)tb * 256 + i * 64 + l];
            vA[i] = Vh[(size_t)tb * 256 + i * 64 + l];
        }
        int i = tb;
        for (; i + 2 <= te; i += 2) {
            const uint4* Kn = Kh + (size_t)(i + 1) * 256;
            const uint4* Vn = Vh + (size_t)(i + 1) * 256;
            #pragma unroll
            for (int q = 0; q < 4; ++q) { kB[q] = Kn[q * 64 + l]; vB[q] = Vn[q * 64 + l]; }
            compute(i, kA, vA);
            if (i + 2 < te) {
                const uint4* K2 = Kh + (size_t)(i + 2) * 256;
                const uint4* V2 = Vh + (size_t)(i + 2) * 256;
                #pragma unroll
                for (int q = 0; q < 4; ++q) { kA[q] = K2[q * 64 + l]; vA[q] = V2[q * 64 + l]; }
            }
            compute(i + 1, kB, vB);
        }
        if ((te - tb) & 1) compute(te - 1, kA, vA);
    }
    lsum += __shfl_xor(lsum, 32);

    if (w == 1) {
        #pragma unroll
        for (int r = 0; r < 16; ++r) {
            int ql = (r & 3) + 8 * (r >> 2) + hi4;
            Op[ql][lc]      = oacc[0][r];
            Op[ql][32 + lc] = oacc[1][r];
        }
        if (hi == 0) { Ml[0][lc] = m; Ml[1][lc] = lsum; }
    }
    __syncthreads();
    if (w == 0) {
        float mo = Ml[0][lc], lo = Ml[1][lc];
        float mm = fmaxf(m, mo);
        float alr = exp2f(m - mm), alo = exp2f(mo - mm);
        float lf = lsum * alr + lo * alo;
        float inv = 1.0f / lf;
        float fr = alr * inv, fo = alo * inv;
        int q0 = jj * 32;
        #pragma unroll
        for (int r = 0; r < 16; ++r) {
            int ql = (r & 3) + 8 * (r >> 2) + hi4;
            float frb = __shfl(fr, ql), fob = __shfl(fo, ql);
            float o0 = oacc[0][r] * frb + Op[ql][lc]      * fob;
            float o1 = oacc[1][r] * frb + Op[ql][32 + lc] * fob;
            int row = q0 + ql;
            O[(size_t)row * 1024 + h * 64 + lc]      = (bf16)o0;
            O[(size_t)row * 1024 + h * 64 + 32 + lc] = (bf16)o1;
        }
    }
}

extern "C" void kernel_launch(void* const* d_in, const int* in_sizes, int n_in,
                              void* d_out, int out_size, void* d_ws, size_t ws_size,
                              hipStream_t stream) {
    const float* X    = (const float*)d_in[0];   // [1,4096,1024]
    const float* Wqkv = (const float*)d_in[1];   // [1024,3072]
    const float* bqkv = (const float*)d_in[2];   // [3072]
    const float* Wo   = (const float*)d_in[3];   // [1024,1024]
    const float* bo   = (const float*)d_in[4];   // [1024]
    float* out = (float*)d_out;

    char* ws = (char*)d_ws;
    const size_t MB = 1024 * 1024;
    bf16*  Xb    = (bf16*)(ws);             //  8 MB [4096][1024]; dead after gemm_qkv
    bf16*  WqkvT = (bf16*)(ws + 8  * MB);   //  6 MB [3072][1024]
    bf16*  WoT   = (bf16*)(ws + 14 * MB);   //  2 MB [1024][1024]
    bf16*  Qb    = (bf16*)(ws + 16 * MB);   //  8 MB [16][4096][64]
    uint4* Kfr   = (uint4*)(ws + 40 * MB);  //  8 MB frag-packed K (written by gemm_qkv)
    uint4* Vfr   = (uint4*)(ws + 48 * MB);  //  8 MB frag-packed V^T (written by gemm_qkv)
    bf16*  Ob    = Xb;                      //  alias: Xb dead before attn writes Ob

    k_prep<<<3072, 256, 0, stream>>>(X, Xb, Wqkv, WqkvT, Wo, WoT);
    k_gemm_qkv<<<768, 256, 0, stream>>>(Xb, WqkvT, bqkv, Qb, (bf16*)Kfr, (bf16*)Vfr);
    k_attn<<<2048, 128, 0, stream>>>(Qb, Kfr, Vfr, Ob);
    k_gemm_out<<<512, 256, 0, stream>>>(Ob, WoT, bo, out);
}